// Round 11
// baseline (34.772 us; speedup 1.0000x reference)
//
#include <hip/hip_runtime.h>

// TT-embedding: voc_quant (32,32,32), emb_quant (8,8,16), ranks (1,8,8,1).
// out[n, pair*16+e2] = sum_r2 A[i0*32+i1][pair*8+r2] * c2[i2][r2*16+e2],
// A = first contraction in bf16 (1 MB, L2-resident).
//
// Ladder: 39.5 -> 38.1 (R5 one-wave/idx) -> 37.3 (R6 contig stores) -> 36.3
// (R8 bf16 A) -> 34.4 (R10 16 idx/wave, 512 blocks). R11: 256 blocks x 512
// threads (1 block/CU, 2 waves/SIMD), 3-deep A prefetch. Confirmed levers:
// fewer wave mem-instrs/idx, fewer longer-lived waves.

#define TT_A_BYTES (1024u * 512u * 2u)   // bf16 A

typedef float f4 __attribute__((ext_vector_type(4)));

// ---- Kernel 1: A[i0][i1][pair*8+r2] = bf16( sum_r1 c0[i0][e0][r1] * c1[i1][r1][e1][r2] )
__global__ __launch_bounds__(256) void tt_precomp_kernel(
    const float* __restrict__ c0,   // [32][8][8]
    const float* __restrict__ c1,   // [32][8][8][8]
    unsigned short* __restrict__ A) // [1024][512] bf16
{
    __shared__ float s0[64];
    __shared__ float s1[512];
    const int i0 = blockIdx.x >> 5;
    const int i1 = blockIdx.x & 31;
    const int t  = threadIdx.x;

    if (t < 16)
        *reinterpret_cast<float4*>(s0 + t * 4) =
            *reinterpret_cast<const float4*>(c0 + i0 * 64 + t * 4);
    if (t < 128)
        *reinterpret_cast<float4*>(s1 + t * 4) =
            *reinterpret_cast<const float4*>(c1 + i1 * 512 + t * 4);
    __syncthreads();

    unsigned short* Ar = A + (size_t)blockIdx.x * 512;
    #pragma unroll
    for (int v = t; v < 512; v += 256) {
        const int pair = v >> 3;            // e0*8 + e1
        const int r2   = v & 7;
        const int e0   = pair >> 3;
        const int e1   = pair & 7;
        float acc = 0.f;
        #pragma unroll
        for (int r1 = 0; r1 < 8; ++r1)
            acc = fmaf(s0[e0 * 8 + r1], s1[r1 * 64 + e1 * 8 + r2], acc);
        unsigned int u = __float_as_uint(acc);              // RNE -> bf16
        Ar[v] = (unsigned short)((u + 0x7fffu + ((u >> 16) & 1u)) >> 16);
    }
}

// ---- Kernel 2 (R11): 512 threads/block, 8 waves, IPW idx/wave, 3-deep prefetch.
template<int IPW>
__global__ __launch_bounds__(512) void tt_emb_kernel512(
    const int* __restrict__ x,
    const unsigned short* __restrict__ A,  // [1024][512] bf16
    const float* __restrict__ c2,          // [32][8][16] = 4096 floats
    float* __restrict__ out,               // [N][1024]
    int N)
{
    __shared__ float s2[4096];      // all of c2, 16 KB
    const int t = threadIdx.x;

    #pragma unroll
    for (int i = 0; i < 2; ++i)
        *reinterpret_cast<float4*>(s2 + (i * 512 + t) * 4) =
            *reinterpret_cast<const float4*>(c2 + (i * 512 + t) * 4);
    __syncthreads();

    const int w = t >> 6;               // wave id 0..7
    const int l = t & 63;               // lane
    const int prow = l >> 2;            // pair sub-index 0..15
    const int eg   = l & 3;             // e2 group
    const int nbase = blockIdx.x * (8 * IPW) + w * IPW;

    int flats[IPW];
    #pragma unroll
    for (int k = 0; k < IPW / 4; ++k) {
        const int4 xv = *reinterpret_cast<const int4*>(x + nbase + 4 * k);
        flats[4 * k]     = xv.x;
        flats[4 * k + 1] = xv.y;
        flats[4 * k + 2] = xv.z;
        flats[4 * k + 3] = xv.w;
    }

    uint4 abuf[3][4];                   // 3-deep pipeline; static idx (full unroll)
    {
        const unsigned short* Ar0 = A + (size_t)((flats[0] >> 5) & 1023) * 512;
        #pragma unroll
        for (int p = 0; p < 4; ++p)
            abuf[0][p] = *reinterpret_cast<const uint4*>(Ar0 + (prow + 16 * p) * 8);
        const unsigned short* Ar1 = A + (size_t)((flats[1] >> 5) & 1023) * 512;
        #pragma unroll
        for (int p = 0; p < 4; ++p)
            abuf[1][p] = *reinterpret_cast<const uint4*>(Ar1 + (prow + 16 * p) * 8);
    }

    #pragma unroll
    for (int g = 0; g < IPW; ++g) {
        if (g + 2 < IPW) {   // 3-deep: issue A loads two indices ahead
            const unsigned short* Ar =
                A + (size_t)((flats[g + 2] >> 5) & 1023) * 512;
            #pragma unroll
            for (int p = 0; p < 4; ++p)
                abuf[(g + 2) % 3][p] =
                    *reinterpret_cast<const uint4*>(Ar + (prow + 16 * p) * 8);
        }

        const int flat = flats[g];
        const float* c2s = s2 + (flat & 31) * 128;
        f4 cv[8];
        #pragma unroll
        for (int r2 = 0; r2 < 8; ++r2)
            cv[r2] = *reinterpret_cast<const f4*>(c2s + r2 * 16 + eg * 4);

        f4* outp = reinterpret_cast<f4*>(out + (size_t)(nbase + g) * 1024);
        const bool pad = (flat == 0);

        #pragma unroll
        for (int p = 0; p < 4; ++p) {
            const uint4 av = abuf[g % 3][p];
            float ax[8];
            ax[0] = __uint_as_float(av.x << 16);
            ax[1] = __uint_as_float(av.x & 0xffff0000u);
            ax[2] = __uint_as_float(av.y << 16);
            ax[3] = __uint_as_float(av.y & 0xffff0000u);
            ax[4] = __uint_as_float(av.z << 16);
            ax[5] = __uint_as_float(av.z & 0xffff0000u);
            ax[6] = __uint_as_float(av.w << 16);
            ax[7] = __uint_as_float(av.w & 0xffff0000u);

            f4 o = {0.f, 0.f, 0.f, 0.f};
            #pragma unroll
            for (int r2 = 0; r2 < 8; ++r2) {
                o.x = fmaf(ax[r2], cv[r2].x, o.x);
                o.y = fmaf(ax[r2], cv[r2].y, o.y);
                o.z = fmaf(ax[r2], cv[r2].z, o.z);
                o.w = fmaf(ax[r2], cv[r2].w, o.w);
            }
            if (pad) o = (f4){0.f, 0.f, 0.f, 0.f};          // padding_idx
            outp[l + 64 * p] = o;       // contiguous 1 KB per wave store
        }
    }
}

// ---- R10 fallback geometry: 256 threads, IPW idx/wave, 2-deep prefetch.
template<int IPW>
__global__ __launch_bounds__(256) void tt_emb_kernel(
    const int* __restrict__ x,
    const unsigned short* __restrict__ A,
    const float* __restrict__ c2,
    float* __restrict__ out,
    int N)
{
    __shared__ float s2[4096];
    const int t = threadIdx.x;

    #pragma unroll
    for (int i = 0; i < 4; ++i)
        *reinterpret_cast<float4*>(s2 + (i * 256 + t) * 4) =
            *reinterpret_cast<const float4*>(c2 + (i * 256 + t) * 4);
    __syncthreads();

    const int w = t >> 6;
    const int l = t & 63;
    const int prow = l >> 2;
    const int eg   = l & 3;
    const int nbase = blockIdx.x * (4 * IPW) + w * IPW;

    int flats[IPW];
    #pragma unroll
    for (int k = 0; k < IPW / 4; ++k) {
        const int4 xv = *reinterpret_cast<const int4*>(x + nbase + 4 * k);
        flats[4 * k]     = xv.x;
        flats[4 * k + 1] = xv.y;
        flats[4 * k + 2] = xv.z;
        flats[4 * k + 3] = xv.w;
    }

    uint4 abuf[2][4];
    {
        const unsigned short* Ar = A + (size_t)((flats[0] >> 5) & 1023) * 512;
        #pragma unroll
        for (int p = 0; p < 4; ++p)
            abuf[0][p] = *reinterpret_cast<const uint4*>(Ar + (prow + 16 * p) * 8);
    }

    #pragma unroll
    for (int g = 0; g < IPW; ++g) {
        if (g < IPW - 1) {
            const unsigned short* Ar =
                A + (size_t)((flats[g + 1] >> 5) & 1023) * 512;
            #pragma unroll
            for (int p = 0; p < 4; ++p)
                abuf[(g + 1) & 1][p] =
                    *reinterpret_cast<const uint4*>(Ar + (prow + 16 * p) * 8);
        }

        const int flat = flats[g];
        const float* c2s = s2 + (flat & 31) * 128;
        f4 cv[8];
        #pragma unroll
        for (int r2 = 0; r2 < 8; ++r2)
            cv[r2] = *reinterpret_cast<const f4*>(c2s + r2 * 16 + eg * 4);

        f4* outp = reinterpret_cast<f4*>(out + (size_t)(nbase + g) * 1024);
        const bool pad = (flat == 0);

        #pragma unroll
        for (int p = 0; p < 4; ++p) {
            const uint4 av = abuf[g & 1][p];
            float ax[8];
            ax[0] = __uint_as_float(av.x << 16);
            ax[1] = __uint_as_float(av.x & 0xffff0000u);
            ax[2] = __uint_as_float(av.y << 16);
            ax[3] = __uint_as_float(av.y & 0xffff0000u);
            ax[4] = __uint_as_float(av.z << 16);
            ax[5] = __uint_as_float(av.z & 0xffff0000u);
            ax[6] = __uint_as_float(av.w << 16);
            ax[7] = __uint_as_float(av.w & 0xffff0000u);

            f4 o = {0.f, 0.f, 0.f, 0.f};
            #pragma unroll
            for (int r2 = 0; r2 < 8; ++r2) {
                o.x = fmaf(ax[r2], cv[r2].x, o.x);
                o.y = fmaf(ax[r2], cv[r2].y, o.y);
                o.z = fmaf(ax[r2], cv[r2].z, o.z);
                o.w = fmaf(ax[r2], cv[r2].w, o.w);
            }
            if (pad) o = (f4){0.f, 0.f, 0.f, 0.f};
            outp[l + 64 * p] = o;
        }
    }
}

// ---- last-resort fallback (ws too small): round-1 LDS kernel
__global__ __launch_bounds__(256) void tt_emb_lds_kernel(
    const int* __restrict__ x,
    const float* __restrict__ c0,
    const float* __restrict__ c1,
    const float* __restrict__ c2,
    float* __restrict__ out)
{
    const int n = blockIdx.x;
    const int t = threadIdx.x;

    __shared__ float s0[64];
    __shared__ float s1[512];
    __shared__ float s2[128];

    const int flat = x[n];
    const int i0 = (flat >> 10) & 31;
    const int i1 = (flat >> 5) & 31;
    const int i2 = flat & 31;

    if (t < 64)  s0[t] = c0[i0 * 64 + t];
    s1[t]        = c1[i1 * 512 + t];
    s1[t + 256]  = c1[i1 * 512 + 256 + t];
    if (t < 128) s2[t] = c2[i2 * 128 + t];
    __syncthreads();

    const int e0  = t >> 5;
    const int e1  = (t >> 2) & 7;
    const int e2b = (t & 3) << 2;

    float tmp[8] = {0.f, 0.f, 0.f, 0.f, 0.f, 0.f, 0.f, 0.f};
    #pragma unroll
    for (int r1 = 0; r1 < 8; ++r1) {
        const float a = s0[e0 * 8 + r1];
        #pragma unroll
        for (int r2 = 0; r2 < 8; ++r2)
            tmp[r2] = fmaf(a, s1[r1 * 64 + e1 * 8 + r2], tmp[r2]);
    }

    float res[4];
    #pragma unroll
    for (int q = 0; q < 4; ++q) {
        float acc = 0.f;
        #pragma unroll
        for (int r2 = 0; r2 < 8; ++r2)
            acc = fmaf(tmp[r2], s2[r2 * 16 + e2b + q], acc);
        res[q] = acc;
    }

    if (flat == 0) { res[0] = res[1] = res[2] = res[3] = 0.f; }

    *reinterpret_cast<float4*>(out + (size_t)n * 1024 + (size_t)t * 4) =
        make_float4(res[0], res[1], res[2], res[3]);
}

extern "C" void kernel_launch(void* const* d_in, const int* in_sizes, int n_in,
                              void* d_out, int out_size, void* d_ws, size_t ws_size,
                              hipStream_t stream) {
    const int*   x  = (const int*)d_in[0];     // 32768 indices
    const float* c0 = (const float*)d_in[1];   // 2048 floats
    const float* c1 = (const float*)d_in[2];   // 16384 floats
    const float* c2 = (const float*)d_in[3];   // 4096 floats
    float* out = (float*)d_out;                // 33554432 fp32

    const int N = in_sizes[0];                 // 32768

    if (ws_size >= TT_A_BYTES && (N % 128) == 0) {
        unsigned short* A = (unsigned short*)d_ws;
        tt_precomp_kernel<<<1024, 256, 0, stream>>>(c0, c1, A);
        tt_emb_kernel512<16><<<N / 128, 512, 0, stream>>>(x, A, c2, out, N);  // 256 blocks
    } else if (ws_size >= TT_A_BYTES && (N % 16) == 0) {
        unsigned short* A = (unsigned short*)d_ws;
        tt_precomp_kernel<<<1024, 256, 0, stream>>>(c0, c1, A);
        tt_emb_kernel<4><<<N / 16, 256, 0, stream>>>(x, A, c2, out, N);
    } else {
        tt_emb_lds_kernel<<<N, 256, 0, stream>>>(x, c0, c1, c2, out);
    }
}

// Round 12
// 33.551 us; speedup vs baseline: 1.0364x; 1.0364x over previous
//
#include <hip/hip_runtime.h>

// TT-embedding: voc_quant (32,32,32), emb_quant (8,8,16), ranks (1,8,8,1).
// out[n, pair*16+e2] = sum_r2 A[i0*32+i1][pair*8+r2] * c2[i2][r2*16+e2],
// A = first contraction in bf16 (1 MB).
//
// Ladder: 39.5 -> 38.1 (R5) -> 37.3 (R6) -> 36.3 (R8 bf16 A) -> 34.4 (R10
// 16 idx/wave). R12: vmcnt decouple — stage each wave's A-rows into LDS up
// front, so the store loop has NO vmem loads: stores never chain behind
// s_waitcnt vmcnt for A (vmcnt retires in order; waiting on a load forces
// all older stores to retire -> per-wave loop gated by HBM write drain).

#define TT_A_BYTES (1024u * 512u * 2u)   // bf16 A

typedef float f4 __attribute__((ext_vector_type(4)));

// ---- Kernel 1: A[i0][i1][pair*8+r2] = bf16( sum_r1 c0[i0][e0][r1] * c1[i1][r1][e1][r2] )
__global__ __launch_bounds__(256) void tt_precomp_kernel(
    const float* __restrict__ c0,   // [32][8][8]
    const float* __restrict__ c1,   // [32][8][8][8]
    unsigned short* __restrict__ A) // [1024][512] bf16
{
    __shared__ float s0[64];
    __shared__ float s1[512];
    const int i0 = blockIdx.x >> 5;
    const int i1 = blockIdx.x & 31;
    const int t  = threadIdx.x;

    if (t < 16)
        *reinterpret_cast<float4*>(s0 + t * 4) =
            *reinterpret_cast<const float4*>(c0 + i0 * 64 + t * 4);
    if (t < 128)
        *reinterpret_cast<float4*>(s1 + t * 4) =
            *reinterpret_cast<const float4*>(c1 + i1 * 512 + t * 4);
    __syncthreads();

    unsigned short* Ar = A + (size_t)blockIdx.x * 512;
    #pragma unroll
    for (int v = t; v < 512; v += 256) {
        const int pair = v >> 3;            // e0*8 + e1
        const int r2   = v & 7;
        const int e0   = pair >> 3;
        const int e1   = pair & 7;
        float acc = 0.f;
        #pragma unroll
        for (int r1 = 0; r1 < 8; ++r1)
            acc = fmaf(s0[e0 * 8 + r1], s1[r1 * 64 + e1 * 8 + r2], acc);
        unsigned int u = __float_as_uint(acc);              // RNE -> bf16
        Ar[v] = (unsigned short)((u + 0x7fffu + ((u >> 16) & 1u)) >> 16);
    }
}

// ---- Kernel 2 (R12): stage A rows in LDS; store loop has zero vmem loads.
// 1024 blocks x 256 thr (4 waves), IPW=8 idx/wave. LDS 48 KB -> 3 blocks/CU.
__global__ __launch_bounds__(256) void tt_emb_stage_kernel(
    const int* __restrict__ x,
    const unsigned short* __restrict__ A,  // [1024][512] bf16
    const float* __restrict__ c2,          // [32][8][16] = 4096 floats
    float* __restrict__ out,               // [N][1024]
    int N)
{
    constexpr int IPW = 8;
    __shared__ float s2[4096];                 // all of c2, 16 KB
    __shared__ unsigned short sA[4 * IPW][512]; // 32 A-rows, 32 KB

    const int t = threadIdx.x;
    const int w = t >> 6;               // wave id 0..3
    const int l = t & 63;               // lane
    const int prow = l >> 2;            // pair sub-index 0..15
    const int eg   = l & 3;             // e2 group
    const int nbase = blockIdx.x * (4 * IPW) + w * IPW;

    // x first (longest dependency chain: x -> A addr -> A load)
    int flats[IPW];
    #pragma unroll
    for (int k = 0; k < IPW / 4; ++k) {
        const int4 xv = *reinterpret_cast<const int4*>(x + nbase + 4 * k);
        flats[4 * k]     = xv.x;
        flats[4 * k + 1] = xv.y;
        flats[4 * k + 2] = xv.z;
        flats[4 * k + 3] = xv.w;
    }

    // issue c2 loads (block-wide: 16 floats = 4 float4 per thread)
    float4 c2r[4];
    #pragma unroll
    for (int i = 0; i < 4; ++i)
        c2r[i] = *reinterpret_cast<const float4*>(c2 + (i * 256 + t) * 4);

    // issue this wave's A-row loads: row g, lane l takes bytes [l*16, l*16+16)
    uint4 aR[IPW];
    #pragma unroll
    for (int g = 0; g < IPW; ++g) {
        const unsigned short* Ar = A + (size_t)((flats[g] >> 5) & 1023) * 512;
        aR[g] = *reinterpret_cast<const uint4*>(Ar + l * 8);
    }

    // write staged data to LDS
    #pragma unroll
    for (int i = 0; i < 4; ++i)
        *reinterpret_cast<float4*>(s2 + (i * 256 + t) * 4) = c2r[i];
    #pragma unroll
    for (int g = 0; g < IPW; ++g)
        reinterpret_cast<uint4*>(&sA[w * IPW + g][0])[l] = aR[g];
    __syncthreads();

    // ---- steady-state loop: ds_read + VALU + stores only (no vmcnt waits)
    #pragma unroll
    for (int g = 0; g < IPW; ++g) {
        const int flat = flats[g];
        const unsigned short* As = &sA[w * IPW + g][0];
        const float* c2s = s2 + (flat & 31) * 128;

        f4 cv[8];
        #pragma unroll
        for (int r2 = 0; r2 < 8; ++r2)
            cv[r2] = *reinterpret_cast<const f4*>(c2s + r2 * 16 + eg * 4);

        f4* outp = reinterpret_cast<f4*>(out + (size_t)(nbase + g) * 1024);
        const bool pad = (flat == 0);

        #pragma unroll
        for (int p = 0; p < 4; ++p) {
            const uint4 av =
                reinterpret_cast<const uint4*>(As)[prow + 16 * p];
            float ax[8];
            ax[0] = __uint_as_float(av.x << 16);
            ax[1] = __uint_as_float(av.x & 0xffff0000u);
            ax[2] = __uint_as_float(av.y << 16);
            ax[3] = __uint_as_float(av.y & 0xffff0000u);
            ax[4] = __uint_as_float(av.z << 16);
            ax[5] = __uint_as_float(av.z & 0xffff0000u);
            ax[6] = __uint_as_float(av.w << 16);
            ax[7] = __uint_as_float(av.w & 0xffff0000u);

            f4 o = {0.f, 0.f, 0.f, 0.f};
            #pragma unroll
            for (int r2 = 0; r2 < 8; ++r2) {
                o.x = fmaf(ax[r2], cv[r2].x, o.x);
                o.y = fmaf(ax[r2], cv[r2].y, o.y);
                o.z = fmaf(ax[r2], cv[r2].z, o.z);
                o.w = fmaf(ax[r2], cv[r2].w, o.w);
            }
            if (pad) o = (f4){0.f, 0.f, 0.f, 0.f};          // padding_idx
            outp[l + 64 * p] = o;       // contiguous 1 KB per wave store
        }
    }
}

// ---- R10 fallback geometry: 256 threads, IPW idx/wave, 2-deep prefetch.
template<int IPW>
__global__ __launch_bounds__(256) void tt_emb_kernel(
    const int* __restrict__ x,
    const unsigned short* __restrict__ A,
    const float* __restrict__ c2,
    float* __restrict__ out,
    int N)
{
    __shared__ float s2[4096];
    const int t = threadIdx.x;

    #pragma unroll
    for (int i = 0; i < 4; ++i)
        *reinterpret_cast<float4*>(s2 + (i * 256 + t) * 4) =
            *reinterpret_cast<const float4*>(c2 + (i * 256 + t) * 4);
    __syncthreads();

    const int w = t >> 6;
    const int l = t & 63;
    const int prow = l >> 2;
    const int eg   = l & 3;
    const int nbase = blockIdx.x * (4 * IPW) + w * IPW;

    int flats[IPW];
    #pragma unroll
    for (int k = 0; k < IPW / 4; ++k) {
        const int4 xv = *reinterpret_cast<const int4*>(x + nbase + 4 * k);
        flats[4 * k]     = xv.x;
        flats[4 * k + 1] = xv.y;
        flats[4 * k + 2] = xv.z;
        flats[4 * k + 3] = xv.w;
    }

    uint4 abuf[2][4];
    {
        const unsigned short* Ar = A + (size_t)((flats[0] >> 5) & 1023) * 512;
        #pragma unroll
        for (int p = 0; p < 4; ++p)
            abuf[0][p] = *reinterpret_cast<const uint4*>(Ar + (prow + 16 * p) * 8);
    }

    #pragma unroll
    for (int g = 0; g < IPW; ++g) {
        if (g < IPW - 1) {
            const unsigned short* Ar =
                A + (size_t)((flats[g + 1] >> 5) & 1023) * 512;
            #pragma unroll
            for (int p = 0; p < 4; ++p)
                abuf[(g + 1) & 1][p] =
                    *reinterpret_cast<const uint4*>(Ar + (prow + 16 * p) * 8);
        }

        const int flat = flats[g];
        const float* c2s = s2 + (flat & 31) * 128;
        f4 cv[8];
        #pragma unroll
        for (int r2 = 0; r2 < 8; ++r2)
            cv[r2] = *reinterpret_cast<const f4*>(c2s + r2 * 16 + eg * 4);

        f4* outp = reinterpret_cast<f4*>(out + (size_t)(nbase + g) * 1024);
        const bool pad = (flat == 0);

        #pragma unroll
        for (int p = 0; p < 4; ++p) {
            const uint4 av = abuf[g & 1][p];
            float ax[8];
            ax[0] = __uint_as_float(av.x << 16);
            ax[1] = __uint_as_float(av.x & 0xffff0000u);
            ax[2] = __uint_as_float(av.y << 16);
            ax[3] = __uint_as_float(av.y & 0xffff0000u);
            ax[4] = __uint_as_float(av.z << 16);
            ax[5] = __uint_as_float(av.z & 0xffff0000u);
            ax[6] = __uint_as_float(av.w << 16);
            ax[7] = __uint_as_float(av.w & 0xffff0000u);

            f4 o = {0.f, 0.f, 0.f, 0.f};
            #pragma unroll
            for (int r2 = 0; r2 < 8; ++r2) {
                o.x = fmaf(ax[r2], cv[r2].x, o.x);
                o.y = fmaf(ax[r2], cv[r2].y, o.y);
                o.z = fmaf(ax[r2], cv[r2].z, o.z);
                o.w = fmaf(ax[r2], cv[r2].w, o.w);
            }
            if (pad) o = (f4){0.f, 0.f, 0.f, 0.f};
            outp[l + 64 * p] = o;
        }
    }
}

// ---- last-resort fallback (ws too small): round-1 LDS kernel
__global__ __launch_bounds__(256) void tt_emb_lds_kernel(
    const int* __restrict__ x,
    const float* __restrict__ c0,
    const float* __restrict__ c1,
    const float* __restrict__ c2,
    float* __restrict__ out)
{
    const int n = blockIdx.x;
    const int t = threadIdx.x;

    __shared__ float s0[64];
    __shared__ float s1[512];
    __shared__ float s2[128];

    const int flat = x[n];
    const int i0 = (flat >> 10) & 31;
    const int i1 = (flat >> 5) & 31;
    const int i2 = flat & 31;

    if (t < 64)  s0[t] = c0[i0 * 64 + t];
    s1[t]        = c1[i1 * 512 + t];
    s1[t + 256]  = c1[i1 * 512 + 256 + t];
    if (t < 128) s2[t] = c2[i2 * 128 + t];
    __syncthreads();

    const int e0  = t >> 5;
    const int e1  = (t >> 2) & 7;
    const int e2b = (t & 3) << 2;

    float tmp[8] = {0.f, 0.f, 0.f, 0.f, 0.f, 0.f, 0.f, 0.f};
    #pragma unroll
    for (int r1 = 0; r1 < 8; ++r1) {
        const float a = s0[e0 * 8 + r1];
        #pragma unroll
        for (int r2 = 0; r2 < 8; ++r2)
            tmp[r2] = fmaf(a, s1[r1 * 64 + e1 * 8 + r2], tmp[r2]);
    }

    float res[4];
    #pragma unroll
    for (int q = 0; q < 4; ++q) {
        float acc = 0.f;
        #pragma unroll
        for (int r2 = 0; r2 < 8; ++r2)
            acc = fmaf(tmp[r2], s2[r2 * 16 + e2b + q], acc);
        res[q] = acc;
    }

    if (flat == 0) { res[0] = res[1] = res[2] = res[3] = 0.f; }

    *reinterpret_cast<float4*>(out + (size_t)n * 1024 + (size_t)t * 4) =
        make_float4(res[0], res[1], res[2], res[3]);
}

extern "C" void kernel_launch(void* const* d_in, const int* in_sizes, int n_in,
                              void* d_out, int out_size, void* d_ws, size_t ws_size,
                              hipStream_t stream) {
    const int*   x  = (const int*)d_in[0];     // 32768 indices
    const float* c0 = (const float*)d_in[1];   // 2048 floats
    const float* c1 = (const float*)d_in[2];   // 16384 floats
    const float* c2 = (const float*)d_in[3];   // 4096 floats
    float* out = (float*)d_out;                // 33554432 fp32

    const int N = in_sizes[0];                 // 32768

    if (ws_size >= TT_A_BYTES && (N % 32) == 0) {
        unsigned short* A = (unsigned short*)d_ws;
        tt_precomp_kernel<<<1024, 256, 0, stream>>>(c0, c1, A);
        tt_emb_stage_kernel<<<N / 32, 256, 0, stream>>>(x, A, c2, out, N);  // R12
    } else if (ws_size >= TT_A_BYTES && (N % 64) == 0) {
        unsigned short* A = (unsigned short*)d_ws;
        tt_precomp_kernel<<<1024, 256, 0, stream>>>(c0, c1, A);
        tt_emb_kernel<16><<<N / 64, 256, 0, stream>>>(x, A, c2, out, N);    // R10
    } else {
        tt_emb_lds_kernel<<<N, 256, 0, stream>>>(x, c0, c1, c2, out);
    }
}